// Round 2
// baseline (29.098 us; speedup 1.0000x reference)
//
#include <hip/hip_runtime.h>

// Adaptive avg pool 2D: (16, 768, 64, 48) f32 -> (16, 768, 7, 7) f32.
// 2 planes per block. Direct HBM->LDS staging via global_load_lds (16B/lane),
// then separable pooling (W then H) in LDS.

#define H_IN 64
#define W_IN 48
#define HO 7
#define WO 7
#define PLANE (H_IN * W_IN)   // 3072 floats = 12 KB
#define PPB 2                 // planes per block

typedef __attribute__((address_space(3))) void  lds_void_t;
typedef const __attribute__((address_space(1))) void gbl_void_t;

__global__ __launch_bounds__(256) void
adaptive_pool_kernel(const float* __restrict__ x, float* __restrict__ out) {
    __shared__ float xs[PPB][PLANE];        // 24 KB
    __shared__ float ts[PPB][H_IN * WO];    // 3.5 KB

    const int tid = threadIdx.x;
    const size_t plane0 = (size_t)blockIdx.x * PPB;
    const float* xp = x + plane0 * PLANE;

    // ---- Stage 0: direct global->LDS, 16 B per lane per issue.
    // Lane order is linear, so the wave-uniform-base + lane*16 DMA layout
    // matches the LDS layout exactly (no padding anywhere).
    #pragma unroll
    for (int p = 0; p < PPB; ++p) {
        #pragma unroll
        for (int i = 0; i < 3; ++i) {
            const int f4 = tid + i * 256;   // float4 index within plane
            __builtin_amdgcn_global_load_lds(
                (gbl_void_t*)(xp + p * PLANE + f4 * 4),
                (lds_void_t*)(&xs[p][f4 * 4]),
                16, 0, 0);
        }
    }
    asm volatile("s_waitcnt vmcnt(0)" ::: "memory");
    __syncthreads();

    // ---- Stage 1: pool along W: ts[p][row][ow] = mean over window.
    // PPB*64*7 = 896 items over 256 threads -> 4 iterations (last partial).
    #pragma unroll
    for (int i = 0; i < 4; ++i) {
        const int item = tid + i * 256;
        if (item < PPB * H_IN * WO) {
            const int p  = item / (H_IN * WO);
            const int r  = item % (H_IN * WO);
            const int row = r / WO;
            const int ow  = r % WO;
            const int ws  = (ow * W_IN) / WO;
            const int we  = ((ow + 1) * W_IN + WO - 1) / WO;
            float s = 0.0f;
            #pragma unroll
            for (int w = 0; w < 8; ++w) {          // max W window = 8
                if (ws + w < we) s += xs[p][row * W_IN + ws + w];
            }
            ts[p][r] = s * (1.0f / (float)(we - ws));
        }
    }
    __syncthreads();

    // ---- Stage 2: pool along H. PPB*49 = 98 outputs.
    if (tid < PPB * HO * WO) {
        const int p  = tid / (HO * WO);
        const int r  = tid % (HO * WO);
        const int oh = r / WO;
        const int ow = r % WO;
        const int hs = (oh * H_IN) / HO;
        const int he = ((oh + 1) * H_IN + HO - 1) / HO;   // window = 10 always
        float s = 0.0f;
        #pragma unroll
        for (int h = 0; h < 10; ++h) {
            if (hs + h < he) s += ts[p][(hs + h) * WO + ow];
        }
        // out index: (plane0 + p)*49 + r == plane0*49 + tid  (contiguous)
        out[plane0 * (HO * WO) + tid] = s * (1.0f / (float)(he - hs));
    }
}

extern "C" void kernel_launch(void* const* d_in, const int* in_sizes, int n_in,
                              void* d_out, int out_size, void* d_ws, size_t ws_size,
                              hipStream_t stream) {
    const float* x = (const float*)d_in[0];
    float* out = (float*)d_out;
    const int nplanes = in_sizes[0] / PLANE;       // 12288
    const int nblocks = (nplanes + PPB - 1) / PPB; // 6144
    adaptive_pool_kernel<<<nblocks, 256, 0, stream>>>(x, out);
}